// Round 5
// baseline (388.641 us; speedup 1.0000x reference)
//
#include <hip/hip_runtime.h>
#include <hip/hip_bf16.h>

#define F 1024
#define S 128
#define H 16
#define D 64
#define CK 64        // k-chunk
#define NCHUNK 16    // 1024/64

typedef short bf16x8 __attribute__((ext_vector_type(8)));
typedef float f32x4  __attribute__((ext_vector_type(4)));

// ws: xs[256 b][16 ch][1024 units] (R3-proven x images) then wb[8 hp][16 ch][2048 units]
#define XS_UNITS ((size_t)4096 * 1024)
#define WB_UNITS ((size_t)128 * 2048)
#define WS_NEED ((XS_UNITS + WB_UNITS) * 16)

// Main LDS (2-head block): phase1 Ws(32K)+xT(16K) aliased with phase2 qk(64K); scratch.
// unit(row,kc) = base + row*8 + (kc ^ (row&7))  [XOR swizzle, conflict-free b128]
struct SmemT {
    union {
        struct { uint4 Ws[2048]; uint4 xT[1024]; } p1;  // 48 KB
        struct { uint4 qk[4096]; } p2;                  // 64 KB: [qs0|ks0|qs1|ks1] x 1024
    } u;
    float wpart[2][4][S];
    float wfin[2][S];
};

struct SmemFb {
    uint4 mat[2048];
    float wpart[4][S];
    float wfin[S];
};

__device__ __forceinline__ unsigned short f2bf(float f) {
    unsigned u = __float_as_uint(f);
    u += 0x7fffu + ((u >> 16) & 1u);   // RNE
    return (unsigned short)(u >> 16);
}

__device__ __forceinline__ unsigned pk2(float a, float b) {
    __hip_bfloat162 h = __float22bfloat162_rn(make_float2(a, b));
    return *(unsigned*)&h;
}

__device__ __forceinline__ uint4 pack8(const float* f) {
    uint4 u;
    u.x = pk2(f[0], f[1]); u.y = pk2(f[2], f[3]);
    u.z = pk2(f[4], f[5]); u.w = pk2(f[6], f[7]);
    return u;
}

typedef __attribute__((address_space(1))) const unsigned int as1_u32;
typedef __attribute__((address_space(3))) unsigned int as3_u32;

__device__ __forceinline__ void async_cp16(const uint4* g, uint4* l) {
    __builtin_amdgcn_global_load_lds((as1_u32*)g, (as3_u32*)l, 16, 0, 0);
}

// ---------------- prep: bf16-convert + transpose/swizzle into DMA-linear images ----------------
__global__ void prep(const float* __restrict__ x,
                     const float* __restrict__ Wq,
                     const float* __restrict__ Wk,
                     uint4* __restrict__ xs,
                     uint4* __restrict__ wb)
{
    __shared__ float tile[64 * 129];
    const int tid = threadIdx.x;
    const int blk = blockIdx.x;
    if (blk < 4096) {
        // x image (R3-proven): (b,ch) -> 64 i-rows x 128 s, transposed to units [s][kc]
        const int b = blk >> 4, ch = blk & 15;
        const float4* src = (const float4*)(x + ((size_t)b * F + ch * CK) * S);
        float4 v[8];
#pragma unroll
        for (int j = 0; j < 8; ++j) v[j] = src[tid + j * 256];
#pragma unroll
        for (int j = 0; j < 8; ++j) {
            const int e4 = tid + j * 256;
            const int i  = e4 >> 5;
            const int sc = (e4 & 31) * 4;
            tile[i * 129 + sc + 0] = v[j].x;
            tile[i * 129 + sc + 1] = v[j].y;
            tile[i * 129 + sc + 2] = v[j].z;
            tile[i * 129 + sc + 3] = v[j].w;
        }
        __syncthreads();
#pragma unroll
        for (int j = 0; j < 4; ++j) {
            const int u   = tid + j * 256;
            const int s   = u >> 3;
            const int kc  = (u & 7) ^ (s & 7);
            float f[8];
#pragma unroll
            for (int jj = 0; jj < 8; ++jj) f[jj] = tile[(kc * 8 + jj) * 129 + s];
            xs[((size_t)(b * NCHUNK + ch)) * 1024 + u] = pack8(f);
        }
    } else {
        // W image: (hp,ch) -> 256 rows [Wq(2hp);Wk(2hp);Wq(2hp+1);Wk(2hp+1)], k-contig, swizzled
        const int blk2 = blk - 4096;          // 0..127
        const int hp = blk2 >> 4, ch = blk2 & 15;
#pragma unroll
        for (int rep = 0; rep < 8; ++rep) {
            const int u   = tid + rep * 256;  // 0..2047
            const int row = u >> 3;
            const int kc  = (u & 7) ^ (row & 7);
            const int hh  = row >> 7;
            const int sub = row & 127;
            const int hg  = hp * 2 + hh;
            const float* src = ((sub < 64) ? (Wq + (size_t)(hg * D + sub) * F)
                                           : (Wk + (size_t)(hg * D + (sub - 64)) * F))
                               + ch * CK + kc * 8;
            float f[8];
            float4 a = ((const float4*)src)[0];
            float4 c = ((const float4*)src)[1];
            f[0]=a.x; f[1]=a.y; f[2]=a.z; f[3]=a.w; f[4]=c.x; f[5]=c.y; f[6]=c.z; f[7]=c.w;
            wb[(size_t)blk2 * 2048 + u] = pack8(f);
        }
    }
}

// ---------------- main: 2 heads/block, pure-DMA staging + MFMA + softmax + folded epilogue ----
__launch_bounds__(512, 4)
__global__ void attn_main(const float* __restrict__ x,
                          const uint4* __restrict__ xs,
                          const uint4* __restrict__ wb,
                          const float* __restrict__ bq,
                          const float* __restrict__ bk,
                          const float* __restrict__ Wo,
                          const float* __restrict__ bo,
                          float* __restrict__ out)
{
    __shared__ SmemT sm;
    const int tid  = threadIdx.x;
    const int lane = tid & 63;
    const int wv   = tid >> 6;      // 0..7
    const int l15  = lane & 15;
    const int q    = lane >> 4;

    // XCD swizzle: each XCD owns a 32-b slab; all head-pairs of a b reuse x_b in L2
    const int g    = blockIdx.x;    // 2048 blocks
    const int xcd  = g & 7;
    const int slot = g >> 3;        // 0..255
    const int b    = xcd * 32 + (slot & 31);
    const int hp   = slot >> 5;     // 0..7

    const float* xb = x  + (size_t)b * (F * S);
    const uint4* xc = xs + ((size_t)b * NCHUNK) * 1024;
    const uint4* wc = wb + ((size_t)hp * NCHUNK) * 2048;

    // ---------------- Phase 1: [Q;K]x2heads (256x128) = W-tile (256x1024) @ x_b ----------------
    const int m0 = (wv & 3) * 64;   // 0..192
    const int n0 = (wv >> 2) * 64;  // 0/64

    f32x4 acc[4][4];
#pragma unroll
    for (int mt = 0; mt < 4; ++mt)
#pragma unroll
        for (int nt = 0; nt < 4; ++nt) acc[mt][nt] = (f32x4){0.f, 0.f, 0.f, 0.f};

    for (int ch = 0; ch < NCHUNK; ++ch) {
        __syncthreads();   // frag reads of chunk ch-1 drained before overwrite
        // --- pure-DMA staging: 48 KB linear copy (pre-swizzled by prep) ---
        const uint4* wg = wc + ch * 2048;
        const uint4* xg = xc + ch * 1024;
#pragma unroll
        for (int g2 = 0; g2 < 4; ++g2)
            async_cp16(wg + g2 * 512 + wv * 64 + lane, sm.u.p1.Ws + g2 * 512 + wv * 64);
#pragma unroll
        for (int g2 = 0; g2 < 2; ++g2)
            async_cp16(xg + g2 * 512 + wv * 64 + lane, sm.u.p1.xT + g2 * 512 + wv * 64);
        __syncthreads();   // DMA arrived (vmcnt drained at barrier)
        // --- MFMA: 2 k-steps of 32 ---
#pragma unroll
        for (int ks = 0; ks < 2; ++ks) {
            bf16x8 af[4], br[4];
#pragma unroll
            for (int mt = 0; mt < 4; ++mt) {
                const int row = m0 + mt * 16 + l15;
                af[mt] = *(const bf16x8*)&sm.u.p1.Ws[row * 8 + ((ks * 4 + q) ^ (row & 7))];
            }
#pragma unroll
            for (int nt = 0; nt < 4; ++nt) {
                const int row = n0 + nt * 16 + l15;
                br[nt] = *(const bf16x8*)&sm.u.p1.xT[row * 8 + ((ks * 4 + q) ^ (row & 7))];
            }
#pragma unroll
            for (int mt = 0; mt < 4; ++mt)
#pragma unroll
                for (int nt = 0; nt < 4; ++nt)
                    acc[mt][nt] = __builtin_amdgcn_mfma_f32_16x16x32_bf16(
                        af[mt], br[nt], acc[mt][nt], 0, 0, 0);
        }
    }

    // ---------------- Epilogue: +bias, cvt bf16, write qs/ks per head (rows=s|t, k=d) --------
    __syncthreads();
    {
        unsigned short* m16 = (unsigned short*)sm.u.p2.qk;
#pragma unroll
        for (int mt = 0; mt < 4; ++mt) {
#pragma unroll
            for (int rr = 0; rr < 4; ++rr) {
                const int m    = m0 + mt * 16 + q * 4 + rr;   // C/D row = (lane>>4)*4 + reg
                const int hh   = m >> 7;
                const int w128 = m & 127;
                const int d    = w128 & 63;
                const int hg   = hp * 2 + hh;
                const float bias = (w128 < 64) ? bq[hg * D + d] : bk[hg * D + d];
                const int ubase  = hh * 2048 + ((w128 < 64) ? 0 : 1024);
#pragma unroll
                for (int nt = 0; nt < 4; ++nt) {
                    const int s = n0 + nt * 16 + l15;          // C/D col = lane&15
                    const float v = acc[mt][nt][rr] + bias;
                    const int unit = ubase + s * 8 + ((d >> 3) ^ (s & 7));
                    m16[unit * 8 + (d & 7)] = f2bf(v);
                }
            }
        }
    }
    __syncthreads();

    // ---------------- Phase 2: per head, scores = Q^T @ K; 4 waves/head, 32 rows/wave --------
    const int hh   = wv >> 2;            // this wave's head
    const int hg   = hp * 2 + hh;
    const int rb   = (wv & 3) * 32;      // score-row base
    const int qsO  = hh * 2048;
    const int ksO  = qsO + 1024;

    f32x4 p[2][8];
#pragma unroll
    for (int mt = 0; mt < 2; ++mt)
#pragma unroll
        for (int nt = 0; nt < 8; ++nt) p[mt][nt] = (f32x4){0.f, 0.f, 0.f, 0.f};

#pragma unroll
    for (int ks = 0; ks < 2; ++ks) {
        bf16x8 a2[2], b2[8];
#pragma unroll
        for (int mt = 0; mt < 2; ++mt) {
            const int row = rb + mt * 16 + l15;
            a2[mt] = *(const bf16x8*)&sm.u.p2.qk[qsO + row * 8 + ((ks * 4 + q) ^ (row & 7))];
        }
#pragma unroll
        for (int nt = 0; nt < 8; ++nt) {
            const int row = nt * 16 + l15;
            b2[nt] = *(const bf16x8*)&sm.u.p2.qk[ksO + row * 8 + ((ks * 4 + q) ^ (row & 7))];
        }
#pragma unroll
        for (int mt = 0; mt < 2; ++mt)
#pragma unroll
            for (int nt = 0; nt < 8; ++nt)
                p[mt][nt] = __builtin_amdgcn_mfma_f32_16x16x32_bf16(a2[mt], b2[nt], p[mt][nt], 0, 0, 0);
    }

    // ---------------- Phase 3+4: softmax rows + fold Wo -> partial w[t] per head --------------
    float pw[8];
#pragma unroll
    for (int nt = 0; nt < 8; ++nt) pw[nt] = 0.f;

#pragma unroll
    for (int mt = 0; mt < 2; ++mt) {
#pragma unroll
        for (int rr = 0; rr < 4; ++rr) {
            const int srow = rb + mt * 16 + q * 4 + rr;
            float mx = p[mt][0][rr];
#pragma unroll
            for (int nt = 1; nt < 8; ++nt) mx = fmaxf(mx, p[mt][nt][rr]);
#pragma unroll
            for (int off = 1; off < 16; off <<= 1) mx = fmaxf(mx, __shfl_xor(mx, off));
            float e[8];
            float l = 0.f;
#pragma unroll
            for (int nt = 0; nt < 8; ++nt) {
                e[nt] = __expf((p[mt][nt][rr] - mx) * 0.125f);   // 1/TEMP
                l += e[nt];
            }
#pragma unroll
            for (int off = 1; off < 16; off <<= 1) l += __shfl_xor(l, off);
            const float c = Wo[srow] / l;
#pragma unroll
            for (int nt = 0; nt < 8; ++nt) pw[nt] = fmaf(c, e[nt], pw[nt]);
        }
    }
#pragma unroll
    for (int nt = 0; nt < 8; ++nt) {
        pw[nt] += __shfl_xor(pw[nt], 16);
        pw[nt] += __shfl_xor(pw[nt], 32);
    }
    if (q == 0) {
#pragma unroll
        for (int nt = 0; nt < 8; ++nt) sm.wpart[hh][wv & 3][nt * 16 + l15] = pw[nt];
    }
    __syncthreads();
    if (tid < 256) {
        const int h2 = tid >> 7, t = tid & 127;
        sm.wfin[h2][t] = sm.wpart[h2][0][t] + sm.wpart[h2][1][t]
                       + sm.wpart[h2][2][t] + sm.wpart[h2][3][t];
    }
    __syncthreads();

    // ---------------- Phase 5: out[b, hg*64+d] = sum_t w[t]*x[b,hg*64+d,t] + bo ---------------
    {
        const int h3   = tid >> 8;          // 0/1
        const int r    = tid & 255;
        const int dd   = r >> 2;
        const int part = r & 3;
        const int hg3  = hp * 2 + h3;
        const float* xv = xb + (size_t)(hg3 * D + dd) * S + part * 32;
        float a5 = 0.f;
#pragma unroll 8
        for (int t = 0; t < 32; ++t) a5 = fmaf(sm.wfin[h3][part * 32 + t], xv[t], a5);
        a5 += __shfl_xor(a5, 1);
        a5 += __shfl_xor(a5, 2);
        if (part == 0) out[(size_t)b * F + hg3 * D + dd] = a5 + bo[0];
    }
}

// ---------------- fallback (R2-proven self-contained) if ws too small ----------------
__launch_bounds__(256, 4)
__global__ void attn_fallback(const float* __restrict__ x,
                              const float* __restrict__ Wq,
                              const float* __restrict__ bq,
                              const float* __restrict__ Wk,
                              const float* __restrict__ bk,
                              const float* __restrict__ Wo,
                              const float* __restrict__ bo,
                              float* __restrict__ out)
{
    __shared__ SmemFb sm;
    const int tid  = threadIdx.x;
    const int lane = tid & 63;
    const int wv   = tid >> 6;
    const int l15  = lane & 15;
    const int q    = lane >> 4;

    const int g    = blockIdx.x;
    const int xcd  = g & 7;
    const int slot = g >> 3;
    const int hg   = slot >> 7;
    const int r0   = slot & 127;
    const int b    = xcd * 32 + (r0 >> 2);
    const int h    = hg * 4 + (r0 & 3);

    const float* xb  = x  + (size_t)b * (F * S);
    const float* wqh = Wq + (size_t)h * D * F;
    const float* wkh = Wk + (size_t)h * D * F;

    const int m0 = (wv & 1) * 64;
    const int n0 = (wv >> 1) * 64;

    f32x4 acc[4][4];
#pragma unroll
    for (int mt = 0; mt < 4; ++mt)
#pragma unroll
        for (int nt = 0; nt < 4; ++nt) acc[mt][nt] = (f32x4){0.f, 0.f, 0.f, 0.f};

    const int mq  = tid >> 2;
    const int kq  = tid & 3;
    const int s0x = (tid & 63) * 2;
    const int iq  = tid >> 6;

    for (int ch = 0; ch < 16; ++ch) {
        const int c0 = ch * 64;
        __syncthreads();
        {
            const int key = mq & 7;
            float f[16];
            const float4* srcq = (const float4*)(wqh + (size_t)mq * F + (c0 + kq * 16));
#pragma unroll
            for (int j = 0; j < 4; ++j) {
                float4 v = srcq[j];
                f[4*j] = v.x; f[4*j+1] = v.y; f[4*j+2] = v.z; f[4*j+3] = v.w;
            }
            sm.mat[mq * 8 + ((kq * 2    ) ^ key)] = pack8(f);
            sm.mat[mq * 8 + ((kq * 2 + 1) ^ key)] = pack8(f + 8);
            const float4* srck = (const float4*)(wkh + (size_t)mq * F + (c0 + kq * 16));
#pragma unroll
            for (int j = 0; j < 4; ++j) {
                float4 v = srck[j];
                f[4*j] = v.x; f[4*j+1] = v.y; f[4*j+2] = v.z; f[4*j+3] = v.w;
            }
            sm.mat[(64 + mq) * 8 + ((kq * 2    ) ^ key)] = pack8(f);
            sm.mat[(64 + mq) * 8 + ((kq * 2 + 1) ^ key)] = pack8(f + 8);
        }
        {
            const float* src = xb + (size_t)(c0 + iq * 16) * S + s0x;
            float fa[8], fb[8];
#pragma unroll
            for (int grp = 0; grp < 2; ++grp) {
#pragma unroll
                for (int j = 0; j < 8; ++j) {
                    float2 v = *(const float2*)(src + (size_t)(grp * 8 + j) * S);
                    fa[j] = v.x; fb[j] = v.y;
                }
                const int kc = iq * 2 + grp;
                sm.mat[1024 + (s0x    ) * 8 + (kc ^ ((s0x    ) & 7))] = pack8(fa);
                sm.mat[1024 + (s0x + 1) * 8 + (kc ^ ((s0x + 1) & 7))] = pack8(fb);
            }
        }
        __syncthreads();
#pragma unroll
        for (int ks = 0; ks < 2; ++ks) {
            bf16x8 af[4], br[4];
#pragma unroll
            for (int mt = 0; mt < 4; ++mt) {
                const int row = m0 + mt * 16 + l15;
                af[mt] = *(const bf16x8*)&sm.mat[row * 8 + ((ks * 4 + q) ^ (row & 7))];
            }
#pragma unroll
            for (int nt = 0; nt < 4; ++nt) {
                const int row = n0 + nt * 16 + l15;
                br[nt] = *(const bf16x8*)&sm.mat[1024 + row * 8 + ((ks * 4 + q) ^ (row & 7))];
            }
#pragma unroll
            for (int mt = 0; mt < 4; ++mt)
#pragma unroll
                for (int nt = 0; nt < 4; ++nt)
                    acc[mt][nt] = __builtin_amdgcn_mfma_f32_16x16x32_bf16(
                        af[mt], br[nt], acc[mt][nt], 0, 0, 0);
        }
    }

    __syncthreads();
    {
        unsigned short* m16 = (unsigned short*)sm.mat;
#pragma unroll
        for (int mt = 0; mt < 4; ++mt) {
#pragma unroll
            for (int rr = 0; rr < 4; ++rr) {
                const int m = m0 + mt * 16 + q * 4 + rr;
                const int d = m & 63;
                const float bias = (m < 64) ? bq[h * D + d] : bk[h * D + d];
                const int base = (m < 64) ? 0 : 8192;
#pragma unroll
                for (int nt = 0; nt < 4; ++nt) {
                    const int s = n0 + nt * 16 + l15;
                    const float v = acc[mt][nt][rr] + bias;
                    const int unit = s * 8 + (((d >> 3)) ^ (s & 7));
                    m16[base + unit * 8 + (d & 7)] = f2bf(v);
                }
            }
        }
    }
    __syncthreads();

    f32x4 p[2][8];
#pragma unroll
    for (int mt = 0; mt < 2; ++mt)
#pragma unroll
        for (int nt = 0; nt < 8; ++nt) p[mt][nt] = (f32x4){0.f, 0.f, 0.f, 0.f};

#pragma unroll
    for (int ks = 0; ks < 2; ++ks) {
        bf16x8 a2[2], b2[8];
#pragma unroll
        for (int mt = 0; mt < 2; ++mt) {
            const int row = wv * 32 + mt * 16 + l15;
            a2[mt] = *(const bf16x8*)&sm.mat[row * 8 + ((ks * 4 + q) ^ (row & 7))];
        }
#pragma unroll
        for (int nt = 0; nt < 8; ++nt) {
            const int row = nt * 16 + l15;
            b2[nt] = *(const bf16x8*)&sm.mat[1024 + row * 8 + ((ks * 4 + q) ^ (row & 7))];
        }
#pragma unroll
        for (int mt = 0; mt < 2; ++mt)
#pragma unroll
            for (int nt = 0; nt < 8; ++nt)
                p[mt][nt] = __builtin_amdgcn_mfma_f32_16x16x32_bf16(a2[mt], b2[nt], p[mt][nt], 0, 0, 0);
    }

    float pw[8];
#pragma unroll
    for (int nt = 0; nt < 8; ++nt) pw[nt] = 0.f;

#pragma unroll
    for (int mt = 0; mt < 2; ++mt) {
#pragma unroll
        for (int rr = 0; rr < 4; ++rr) {
            const int srow = wv * 32 + mt * 16 + q * 4 + rr;
            float mx = p[mt][0][rr];
#pragma unroll
            for (int nt = 1; nt < 8; ++nt) mx = fmaxf(mx, p[mt][nt][rr]);
#pragma unroll
            for (int off = 1; off < 16; off <<= 1) mx = fmaxf(mx, __shfl_xor(mx, off));
            float e[8];
            float l = 0.f;
#pragma unroll
            for (int nt = 0; nt < 8; ++nt) {
                e[nt] = __expf((p[mt][nt][rr] - mx) * 0.125f);
                l += e[nt];
            }
#pragma unroll
            for (int off = 1; off < 16; off <<= 1) l += __shfl_xor(l, off);
            const float c = Wo[srow] / l;
#pragma unroll
            for (int nt = 0; nt < 8; ++nt) pw[nt] = fmaf(c, e[nt], pw[nt]);
        }
    }
#pragma unroll
    for (int nt = 0; nt < 8; ++nt) {
        pw[nt] += __shfl_xor(pw[nt], 16);
        pw[nt] += __shfl_xor(pw[nt], 32);
    }
    if (q == 0) {
#pragma unroll
        for (int nt = 0; nt < 8; ++nt) sm.wpart[wv][nt * 16 + l15] = pw[nt];
    }
    __syncthreads();
    if (tid < S)
        sm.wfin[tid] = sm.wpart[0][tid] + sm.wpart[1][tid] + sm.wpart[2][tid] + sm.wpart[3][tid];
    __syncthreads();

    {
        const int dd   = tid >> 2;
        const int part = tid & 3;
        const float* xv = xb + (size_t)(h * D + dd) * S + part * 32;
        float a5 = 0.f;
#pragma unroll 8
        for (int t = 0; t < 32; ++t) a5 = fmaf(sm.wfin[part * 32 + t], xv[t], a5);
        a5 += __shfl_xor(a5, 1);
        a5 += __shfl_xor(a5, 2);
        if (part == 0) out[(size_t)b * F + h * D + dd] = a5 + bo[0];
    }
}

extern "C" void kernel_launch(void* const* d_in, const int* in_sizes, int n_in,
                              void* d_out, int out_size, void* d_ws, size_t ws_size,
                              hipStream_t stream) {
    const float* x  = (const float*)d_in[0];
    const float* Wq = (const float*)d_in[1];
    const float* bq = (const float*)d_in[2];
    const float* Wk = (const float*)d_in[3];
    const float* bk = (const float*)d_in[4];
    const float* Wo = (const float*)d_in[5];
    const float* bo = (const float*)d_in[6];
    float* out = (float*)d_out;

    if (ws_size >= WS_NEED) {
        uint4* xs  = (uint4*)d_ws;
        uint4* wbp = (uint4*)((char*)d_ws + XS_UNITS * 16);
        prep<<<dim3(4096 + 128), dim3(256), 0, stream>>>(x, Wq, Wk, xs, wbp);
        attn_main<<<dim3(2048), dim3(512), 0, stream>>>(x, xs, wbp, bq, bk, Wo, bo, out);
    } else {
        attn_fallback<<<dim3(256 * H), dim3(256), 0, stream>>>(x, Wq, bq, Wk, bk, Wo, bo, out);
    }
}